// Round 11
// baseline (444.436 us; speedup 1.0000x reference)
//
#include <hip/hip_runtime.h>
#include <hip/hip_bf16.h>
#include <math.h>

#define DIMC   256
#define LSP    4096
#define BATCH  8
#define DINNER 512
#define NHEADS 8
#define HEADDIM 64
#define DSTATE 64
#define CONVDIM 640
#define DPROJ  1160
#define MPAD   1280
#define CHUNK  256
#define NCHUNK 16

typedef unsigned short u16;
typedef __attribute__((ext_vector_type(8))) unsigned short u16x8;
typedef __attribute__((ext_vector_type(8))) short s16x8;
typedef __attribute__((ext_vector_type(4))) float f32x4;

#define MFMA16(a,b,c) __builtin_amdgcn_mfma_f32_16x16x32_bf16((s16x8)(a),(s16x8)(b),(c),0,0,0)

__device__ __forceinline__ float bf2f(u16 u){ return __uint_as_float(((unsigned int)u)<<16); }
__device__ __forceinline__ u16 f2bf(float f){
  unsigned int x = __float_as_uint(f);
  unsigned int r = (x + 0x7fffu + ((x>>16)&1u)) >> 16;
  return (u16)r;
}
__device__ __forceinline__ float softplusf(float x){ return (x > 20.f) ? x : __logf(1.f + __expf(x)); }
__device__ __forceinline__ float siluf(float x){ return x * __builtin_amdgcn_rcpf(1.f + __expf(-x)); }

// ---------------- weight fp32 -> bf16 (with trailing-row zero pad) ----------------
__global__ void convert_w(const float* __restrict__ src, u16* __restrict__ dst,
                          int total, int valid){
  int i = blockIdx.x*256 + threadIdx.x;
  if (i >= total) return;
  dst[i] = (i < valid) ? f2bf(src[i]) : (u16)0;
}

// ---------------- out_proj weight * rmsw fold -> bf16 ----------------
__global__ void convert_w_rms(const float* __restrict__ src, const float* __restrict__ rmsw,
                              u16* __restrict__ dst){
  int i = blockIdx.x*256 + threadIdx.x;
  if (i >= DIMC*DINNER) return;
  dst[i] = f2bf(src[i] * rmsw[i & (DINNER-1)]);
}

// ---------------- LayerNorm: x [b][c][l] fp32 -> XNT [b][l][c] bf16 ----------------
__global__ void ln_kernel(const float* __restrict__ X, const float* __restrict__ lnw,
                          const float* __restrict__ lnb, u16* __restrict__ XNT) {
  int pos = blockIdx.x*256 + threadIdx.x;
  int b = pos >> 12, l = pos & (LSP-1);
  const float* xb = X + ((size_t)b*DIMC)*LSP + l;
  float sum=0.f, sq=0.f;
  for (int c=0;c<DIMC;c++){ float v=xb[(size_t)c*LSP]; sum+=v; sq+=v*v; }
  float mu = sum*(1.f/DIMC);
  float var = sq*(1.f/DIMC) - mu*mu;
  float rs = rsqrtf(var + 1e-5f);
  u16* ob = XNT + ((size_t)(b*LSP + l))*DIMC;
  for (int c0=0;c0<DIMC;c0+=8){
    u16x8 v8;
    #pragma unroll
    for(int j=0;j<8;j++){
      float v = xb[(size_t)(c0+j)*LSP];
      v8[j] = f2bf((v-mu)*rs*lnw[c0+j] + lnb[c0+j]);
    }
    *(u16x8*)&ob[c0] = v8;
  }
}

// ---------------- Fused in_proj GEMM: XNT tile LDS-resident, loop over 5 proj tiles.
__global__ __launch_bounds__(256,2) void gemm_in_fused(
    const u16* __restrict__ W, const u16* __restrict__ XNT,
    u16* __restrict__ ZT, u16* __restrict__ XBC, u16* __restrict__ DT){
  __shared__ u16 Xs[128][264];
  __shared__ u16 Ws[128][32];
  int tid=threadIdx.x, w=tid>>6, lane=tid&63, l15=lane&15, quad=lane>>4;
  int n0=blockIdx.x*128, mh=blockIdx.y, b=blockIdx.z;
  {
    const u16* src = XNT + ((size_t)(b*LSP + n0))*DIMC;
    #pragma unroll
    for (int i=0;i<16;i++){
      int g = i*256 + tid;
      int row = g>>5, c8 = (g&31)*8;
      *(u16x8*)&Xs[row][c8] = *(const u16x8*)&src[(size_t)row*DIMC + c8];
    }
  }
  for (int pti=0; pti<5; pti++){
    int ptg = mh*5 + pti;
    int m0 = ptg*128;
    f32x4 acc[4][4];
    #pragma unroll
    for(int i=0;i<4;i++)
      #pragma unroll
      for(int j=0;j<4;j++) acc[i][j]=(f32x4){0.f,0.f,0.f,0.f};
    for (int k0=0;k0<DIMC;k0+=32){
      __syncthreads();
      {
        int ch = tid*2;
        int r = ch>>2, o=(ch&3)*8;
        *(u16x8*)&Ws[r][o] = *(const u16x8*)&W[(size_t)(m0+r)*DIMC + k0 + o];
        ch++; r = ch>>2; o=(ch&3)*8;
        *(u16x8*)&Ws[r][o] = *(const u16x8*)&W[(size_t)(m0+r)*DIMC + k0 + o];
      }
      __syncthreads();
      u16x8 af[4], bfr[4];
      if (ptg < 4){
        #pragma unroll
        for(int mt=0;mt<4;mt++) af[mt] = *(const u16x8*)&Xs[(w>>1)*64+mt*16+l15][k0+quad*8];
        #pragma unroll
        for(int nt=0;nt<4;nt++) bfr[nt] = *(const u16x8*)&Ws[(w&1)*64+nt*16+l15][quad*8];
      } else {
        #pragma unroll
        for(int mt=0;mt<4;mt++) af[mt] = *(const u16x8*)&Ws[(w>>1)*64+mt*16+l15][quad*8];
        #pragma unroll
        for(int nt=0;nt<4;nt++) bfr[nt] = *(const u16x8*)&Xs[(w&1)*64+nt*16+l15][k0+quad*8];
      }
      #pragma unroll
      for(int mt=0;mt<4;mt++)
        #pragma unroll
        for(int nt=0;nt<4;nt++)
          acc[mt][nt]=MFMA16(af[mt],bfr[nt],acc[mt][nt]);
    }
    if (ptg < 4){
      #pragma unroll
      for(int mt=0;mt<4;mt++)
        #pragma unroll
        for(int nt=0;nt<4;nt++)
          #pragma unroll
          for(int r=0;r<4;r++){
            int lrow = n0 + (w>>1)*64 + mt*16 + quad*4 + r;
            int dcol = m0 + (w&1)*64 + nt*16 + l15;
            ZT[((size_t)b*LSP + lrow)*DINNER + dcol] = f2bf(acc[mt][nt][r]);
          }
    } else {
      #pragma unroll
      for(int mt=0;mt<4;mt++)
        #pragma unroll
        for(int nt=0;nt<4;nt++)
          #pragma unroll
          for(int r=0;r<4;r++){
            int prow = m0 + (w>>1)*64 + mt*16 + quad*4 + r;
            if (prow>=DPROJ) continue;
            int col = n0 + (w&1)*64 + nt*16 + l15;
            u16 v = f2bf(acc[mt][nt][r]);
            if (prow<DINNER+CONVDIM)  XBC[((size_t)b*CONVDIM+(prow-DINNER))*LSP+col]=v;
            else                      DT[((size_t)b*NHEADS+(prow-DINNER-CONVDIM))*LSP+col]=v;
          }
    }
  }
}

// ---------------- GEMM2 (MFMA): W2' [256x512] x g [b,l,512], *rinv[l] + x -> fp32 ----
__global__ void gemm_out_mfma(const u16* __restrict__ A, const u16* __restrict__ Bm,
                              const float* __restrict__ Res, float* __restrict__ Out){
  __shared__ u16 As[128][32];
  __shared__ u16 Bs[128][32];
  __shared__ float rinv[128];
  int tid=threadIdx.x, w=tid>>6, lane=tid&63, l15=lane&15, quad=lane>>4;
  int b=blockIdx.z, m0=blockIdx.y*128, n0=blockIdx.x*128;
  const u16* Bb = Bm + ((size_t)b*LSP + n0)*DINNER;
  for (int rr=w; rr<128; rr+=4){
    u16x8 v = *(const u16x8*)&Bb[(size_t)rr*DINNER + lane*8];
    float s=0.f;
    #pragma unroll
    for(int j=0;j<8;j++){ float f=bf2f(v[j]); s+=f*f; }
    #pragma unroll
    for(int o=32;o>0;o>>=1) s += __shfl_xor(s,o,64);
    if (lane==0) rinv[rr] = rsqrtf(s*(1.f/DINNER) + 1e-5f);
  }
  f32x4 acc[4][4];
  #pragma unroll
  for(int i=0;i<4;i++)
    #pragma unroll
    for(int j=0;j<4;j++) acc[i][j] = (f32x4){0.f,0.f,0.f,0.f};
  for (int k0=0;k0<DINNER;k0+=32){
    __syncthreads();
    {
      int ch = tid*2;
      int r = ch>>2, o=(ch&3)*8;
      *(u16x8*)&As[r][o] = *(const u16x8*)&A[(size_t)(m0+r)*DINNER + k0 + o];
      *(u16x8*)&Bs[r][o] = *(const u16x8*)&Bb[(size_t)r*DINNER + k0 + o];
      ch++; r = ch>>2; o=(ch&3)*8;
      *(u16x8*)&As[r][o] = *(const u16x8*)&A[(size_t)(m0+r)*DINNER + k0 + o];
      *(u16x8*)&Bs[r][o] = *(const u16x8*)&Bb[(size_t)r*DINNER + k0 + o];
    }
    __syncthreads();
    u16x8 af[4], bfr[4];
    #pragma unroll
    for(int mt=0;mt<4;mt++) af[mt] = *(const u16x8*)&As[(w>>1)*64+mt*16+l15][quad*8];
    #pragma unroll
    for(int nt=0;nt<4;nt++) bfr[nt] = *(const u16x8*)&Bs[(w&1)*64+nt*16+l15][quad*8];
    #pragma unroll
    for(int mt=0;mt<4;mt++)
      #pragma unroll
      for(int nt=0;nt<4;nt++)
        acc[mt][nt]=MFMA16(af[mt],bfr[nt],acc[mt][nt]);
  }
  #pragma unroll
  for(int mt=0;mt<4;mt++)
    #pragma unroll
    for(int nt=0;nt<4;nt++){
      float rv = rinv[(w&1)*64 + nt*16 + l15];
      #pragma unroll
      for(int r=0;r<4;r++){
        int row = m0 + (w>>1)*64 + mt*16 + quad*4 + r;
        int col = n0 + (w&1)*64 + nt*16 + l15;
        size_t oi = ((size_t)b*DIMC+row)*LSP+col;
        Out[oi] = acc[mt][nt][r]*rv + Res[oi];
      }
    }
}

// ---------------- Depthwise 3x3 conv + bias + SiLU, IN-PLACE on XBC ----------------
__global__ void conv_kernel(u16* __restrict__ XBC, const float* __restrict__ CW,
                            const float* __restrict__ CB){
  int ch = blockIdx.x, b = blockIdx.y, tid = threadIdx.x;
  __shared__ float plane[66*66];
  u16* base = XBC + ((size_t)b*CONVDIM + ch)*LSP;
  for (int idx=tid; idx<66*66; idx+=256){
    int yy = idx/66 - 1, xx = idx%66 - 1;
    float v = 0.f;
    if (yy>=0 && yy<64 && xx>=0 && xx<64) v = bf2f(base[yy*64+xx]);
    plane[idx] = v;
  }
  float wg[9];
  #pragma unroll
  for (int t=0;t<9;t++) wg[t] = CW[ch*9+t];
  float bias = CB[ch];
  __syncthreads();
  for (int r=0;r<16;r++){
    int pix = tid + r*256;
    int y = pix>>6, x = pix&63;
    float s=0.f;
    #pragma unroll
    for(int dy=0;dy<3;dy++)
      #pragma unroll
      for(int dx=0;dx<3;dx++) s += plane[(y+dy)*66 + x+dx]*wg[dy*3+dx];
    base[pix] = f2bf(siluf(s + bias));
  }
}

// ---------------- transpose post-conv B/C planar [n][l] -> BCT [b][l][128] ----------
__global__ void xpose_bc(const u16* __restrict__ XBC, u16* __restrict__ BCT){
  int lb = blockIdx.x, b = blockIdx.y, tid = threadIdx.x;
  __shared__ u16 T[64][136];
  int l0 = lb*64;
  #pragma unroll
  for(int i=0;i<4;i++){
    int idx = i*256 + tid;
    int n = idx>>3, l8 = (idx&7)*8;
    u16x8 v = *(const u16x8*)&XBC[((size_t)b*CONVDIM + DINNER + n)*LSP + l0 + l8];
    #pragma unroll
    for(int j=0;j<8;j++) T[l8+j][n] = v[j];
  }
  __syncthreads();
  #pragma unroll
  for(int i=0;i<4;i++){
    int idx = i*256 + tid;
    int l = idx>>4, n8 = (idx&15)*8;
    *(u16x8*)&BCT[((size_t)(b*LSP + l0 + l))*128 + n8] = *(const u16x8*)&T[l][n8];
  }
}

// ---------------- SSD pre: dt softplus + per-chunk cumsum, done ONCE ----------------
__global__ void ssd_pre_kernel(const u16* __restrict__ DT, const float* __restrict__ A_log,
                               const float* __restrict__ dt_bias, float* __restrict__ ACS,
                               float* __restrict__ DTV, float* __restrict__ DASUM){
  int c=blockIdx.x, h=blockIdx.y, b=blockIdx.z, tid=threadIdx.x;
  __shared__ float acs[CHUNK];
  size_t base = ((size_t)b*NHEADS+h)*LSP + c*CHUNK + tid;
  float raw = bf2f(DT[base]);
  float dtv = softplusf(raw + dt_bias[h]);
  float Ah = -__expf(A_log[h]);
  acs[tid] = dtv*Ah;
  __syncthreads();
  for(int o=1;o<256;o<<=1){
    float add=(tid>=o)?acs[tid-o]:0.f;
    __syncthreads(); acs[tid]+=add; __syncthreads();
  }
  ACS[base] = acs[tid];
  DTV[base] = dtv;
  if (tid==CHUNK-1) DASUM[((size_t)b*NHEADS+h)*NCHUNK+c] = acs[tid];
}

// ---------------- SSD states (MFMA, barrier-free): direct planar reads ----------------
__global__ __launch_bounds__(256,8) void ssd_states_mfma(
    const float* __restrict__ ACS, const float* __restrict__ DTV,
    const float* __restrict__ DASUM, const u16* __restrict__ XBC,
    float* __restrict__ STATES){
  int c=blockIdx.x, h=blockIdx.y, b=blockIdx.z;
  int tid=threadIdx.x, w=tid>>6, lane=tid&63, l15=lane&15, quad=lane>>4;
  __shared__ float wdt[CHUNK];
  {
    size_t base = ((size_t)b*NHEADS+h)*LSP + c*CHUNK + tid;
    float atot = DASUM[((size_t)b*NHEADS+h)*NCHUNK+c];
    wdt[tid] = DTV[base]*__expf(atot - ACS[base]);
  }
  __syncthreads();
  f32x4 acc[4];
  #pragma unroll
  for(int i=0;i<4;i++) acc[i] = (f32x4){0.f,0.f,0.f,0.f};
  size_t cb = (size_t)c*CHUNK;
  const u16* Xrow = XBC + ((size_t)b*CONVDIM + h*HEADDIM + w*16 + l15)*LSP + cb;
  #pragma unroll
  for(int k32=0;k32<8;k32++){
    int t0 = k32*32 + quad*8;
    u16x8 xv = *(const u16x8*)&Xrow[t0];
    u16x8 a;
    #pragma unroll
    for(int j=0;j<8;j++) a[j] = f2bf(bf2f(xv[j]) * wdt[t0+j]);
    #pragma unroll
    for(int nt=0;nt<4;nt++){
      u16x8 bb = *(const u16x8*)&XBC[((size_t)b*CONVDIM + DINNER + nt*16+l15)*LSP + cb + t0];
      acc[nt]=MFMA16(a,bb,acc[nt]);
    }
  }
  float* dst = STATES + (((size_t)b*NHEADS+h)*NCHUNK+c)*4096;
  #pragma unroll
  for(int nt=0;nt<4;nt++)
    #pragma unroll
    for(int r=0;r<4;r++)
      dst[(w*16+quad*4+r)*64 + nt*16+l15] = acc[nt][r];
}

// ---------------- inter-chunk scan -> PREVB bf16 [p][n] per (b,h,c) ----------------
__global__ void ssd_scan_kernel(const float* __restrict__ STATES, const float* __restrict__ DASUM,
                                u16* __restrict__ PREVB){
  int g = blockIdx.x, h = blockIdx.y, b = blockIdx.z, tid = threadIdx.x;
  int e = g*256 + tid;
  size_t hb = (size_t)b*NHEADS + h;
  size_t base = hb*NCHUNK*4096 + e;
  float s = 0.f;
  for (int cc=0;cc<NCHUNK;cc++){
    PREVB[base + (size_t)cc*4096] = f2bf(s);
    s = s*__expf(DASUM[hb*NCHUNK + cc]) + STATES[base + (size_t)cc*4096];
  }
}

// ---------------- SSD Y (MFMA, band per block, barrier-free main loop) --------------
__global__ __launch_bounds__(256,6) void ssd_y_mfma(
    const float* __restrict__ ACS, const float* __restrict__ DTV,
    const u16* __restrict__ XBC, const u16* __restrict__ BCT,
    const float* __restrict__ Dp, const u16* __restrict__ PREVB,
    const u16* __restrict__ ZT, u16* __restrict__ YG){
  int bx = blockIdx.x; int c = bx>>2, tb = bx&3;
  int h = blockIdx.y, b = blockIdx.z;
  int tid=threadIdx.x, w=tid>>6, lane=tid&63, l15=lane&15, quad=lane>>4;
  __shared__ float acs[CHUNK];
  __shared__ float dtv[CHUNK];
  __shared__ u16 P[4][16][72];
  {
    size_t base = ((size_t)b*NHEADS+h)*LSP + c*CHUNK + tid;
    acs[tid] = ACS[base];
    dtv[tid] = DTV[base];
  }
  __syncthreads();
  size_t lchunk = (size_t)b*LSP + (size_t)c*CHUNK;
  int trow = w*16 + l15;
  const u16* Crow = BCT + (lchunk + tb*64 + trow)*128 + 64;
  u16x8 ca0 = *(const u16x8*)&Crow[quad*8];
  u16x8 ca1 = *(const u16x8*)&Crow[32+quad*8];
  f32x4 Yd[4], Yo[4];
  #pragma unroll
  for(int i=0;i<4;i++){ Yd[i]=(f32x4){0.f,0.f,0.f,0.f}; Yo[i]=(f32x4){0.f,0.f,0.f,0.f}; }
  // Y_off (unscaled): C . prev
  {
    const u16* Pg = PREVB + (((size_t)b*NHEADS+h)*NCHUNK + c)*4096;
    #pragma unroll
    for(int pt=0;pt<4;pt++){
      u16x8 b0 = *(const u16x8*)&Pg[(pt*16+l15)*64 + quad*8];
      u16x8 b1 = *(const u16x8*)&Pg[(pt*16+l15)*64 + 32 + quad*8];
      Yo[pt]=MFMA16(ca0,b0,Yo[pt]);
      Yo[pt]=MFMA16(ca1,b1,Yo[pt]);
    }
  }
  int tloc = tb*64 + w*16 + quad*4;
  float acst[4];
  #pragma unroll
  for(int r=0;r<4;r++) acst[r] = acs[tloc+r];
  float Dh = Dp[h];
  const u16* Xbase = XBC + ((size_t)b*CONVDIM + h*HEADDIM)*LSP + (size_t)c*CHUNK;
  for(int sb=0; sb<=tb; sb++){
    f32x4 S[4];
    #pragma unroll
    for(int st=0;st<4;st++){
      S[st]=(f32x4){0.f,0.f,0.f,0.f};
      const u16* Brow = BCT + (lchunk + sb*64 + st*16 + l15)*128;
      u16x8 b0 = *(const u16x8*)&Brow[quad*8];
      u16x8 b1 = *(const u16x8*)&Brow[32+quad*8];
      S[st]=MFMA16(ca0,b0,S[st]);
      S[st]=MFMA16(ca1,b1,S[st]);
    }
    if (sb < tb){
      #pragma unroll
      for(int st=0;st<4;st++){
        int s = sb*64 + st*16 + l15;
        float as = acs[s], dv = dtv[s];
        #pragma unroll
        for(int r=0;r<4;r++)
          P[w][quad*4+r][st*16+l15] = f2bf(S[st][r]*__expf(acst[r]-as)*dv);
      }
    } else {
      #pragma unroll
      for(int st=0;st<4;st++){
        int s = sb*64 + st*16 + l15;
        float as = acs[s], dv = dtv[s];
        #pragma unroll
        for(int r=0;r<4;r++){
          int t = tloc + r;
          float pv;
          if (s < t)       pv = S[st][r]*__expf(acst[r]-as)*dv;
          else if (s == t) pv = S[st][r]*dv + Dh;
          else             pv = 0.f;
          P[w][quad*4+r][st*16+l15] = f2bf(pv);
        }
      }
    }
    u16x8 p0 = *(const u16x8*)&P[w][l15][quad*8];
    u16x8 p1 = *(const u16x8*)&P[w][l15][32+quad*8];
    #pragma unroll
    for(int pt=0;pt<4;pt++){
      const u16* Xrow = Xbase + (size_t)(pt*16+l15)*LSP + sb*64;
      u16x8 x0 = *(const u16x8*)&Xrow[quad*8];
      u16x8 x1 = *(const u16x8*)&Xrow[32+quad*8];
      Yd[pt]=MFMA16(p0,x0,Yd[pt]);
      Yd[pt]=MFMA16(p1,x1,Yd[pt]);
    }
  }
  // epilogue: y = Yd + exp(acs[t])*Yo; gate with silu(z); write YG [l][d]
  float eat[4];
  #pragma unroll
  for(int r=0;r<4;r++) eat[r] = __expf(acst[r]);
  size_t lbase = lchunk + tb*64;
  #pragma unroll
  for(int pt=0;pt<4;pt++){
    #pragma unroll
    for(int r=0;r<4;r++){
      int tl = w*16 + quad*4 + r;
      int p = pt*16 + l15;
      float y = Yd[pt][r] + eat[r]*Yo[pt][r];
      size_t oi = (lbase + tl)*DINNER + h*HEADDIM + p;
      float zv = bf2f(ZT[oi]);
      YG[oi] = f2bf(y * siluf(zv));
    }
  }
}

extern "C" void kernel_launch(void* const* d_in, const int* in_sizes, int n_in,
                              void* d_out, int out_size, void* d_ws, size_t ws_size,
                              hipStream_t stream) {
  const float* x     = (const float*)d_in[0];
  const float* lnw   = (const float*)d_in[1];
  const float* lnb   = (const float*)d_in[2];
  const float* inpw  = (const float*)d_in[3];
  const float* convw = (const float*)d_in[4];
  const float* convb = (const float*)d_in[5];
  const float* alog  = (const float*)d_in[6];
  const float* Dp    = (const float*)d_in[7];
  const float* dtbi  = (const float*)d_in[8];
  const float* rmsw  = (const float*)d_in[9];
  const float* outw  = (const float*)d_in[10];
  float* out = (float*)d_out;

  char* ws = (char*)d_ws;
  size_t off = 0;
  auto alloc = [&](size_t bytes)->void*{ void* p = ws+off; off += (bytes+255)&~(size_t)255; return p; };
  u16*   WPIN   = (u16*)  alloc((size_t)MPAD*DIMC*2);
  u16*   WPOUT  = (u16*)  alloc((size_t)DIMC*DINNER*2);
  char*  RA     = (char*) alloc((size_t)BATCH*NHEADS*NCHUNK*4096*4);
  u16*   XNT    = (u16*)RA;
  float* STATES = (float*)RA;
  u16*   ZT     = (u16*)  alloc((size_t)BATCH*LSP*DINNER*2);
  u16*   XBC    = (u16*)  alloc((size_t)BATCH*CONVDIM*LSP*2);
  u16*   DTb    = (u16*)  alloc((size_t)BATCH*NHEADS*LSP*2);
  u16*   PREVB  = (u16*)  alloc((size_t)BATCH*NHEADS*NCHUNK*4096*2);
  u16*   BCT    = (u16*)  alloc((size_t)BATCH*LSP*128*2);
  float* DASUM  = (float*)alloc((size_t)BATCH*NHEADS*NCHUNK*4);
  float* ACS    = (float*)alloc((size_t)BATCH*NHEADS*LSP*4);
  float* DTV    = (float*)alloc((size_t)BATCH*NHEADS*LSP*4);
  u16*   YG     = (u16*)  alloc((size_t)BATCH*LSP*DINNER*2);

  convert_w<<<(MPAD*DIMC+255)/256,256,0,stream>>>(inpw, WPIN, MPAD*DIMC, DPROJ*DIMC);
  convert_w_rms<<<(DIMC*DINNER+255)/256,256,0,stream>>>(outw, rmsw, WPOUT);
  ln_kernel<<<dim3(BATCH*LSP/256),256,0,stream>>>(x,lnw,lnb,XNT);
  gemm_in_fused<<<dim3(LSP/128,2,BATCH),256,0,stream>>>(WPIN, XNT, ZT, XBC, DTb);
  conv_kernel<<<dim3(CONVDIM,BATCH),256,0,stream>>>(XBC, convw, convb);
  xpose_bc<<<dim3(LSP/64,BATCH),256,0,stream>>>(XBC, BCT);
  ssd_pre_kernel<<<dim3(NCHUNK,NHEADS,BATCH),256,0,stream>>>(DTb, alog, dtbi, ACS, DTV, DASUM);
  ssd_states_mfma<<<dim3(NCHUNK,NHEADS,BATCH),256,0,stream>>>(ACS,DTV,DASUM,XBC,STATES);
  ssd_scan_kernel<<<dim3(16,NHEADS,BATCH),256,0,stream>>>(STATES,DASUM,PREVB);
  ssd_y_mfma<<<dim3(NCHUNK*4,NHEADS,BATCH),256,0,stream>>>(ACS,DTV,XBC,BCT,Dp,PREVB,ZT,YG);
  gemm_out_mfma<<<dim3(LSP/128,DIMC/128,BATCH),256,0,stream>>>(WPOUT, YG, x, out);
}

// Round 12
// 350.709 us; speedup vs baseline: 1.2673x; 1.2673x over previous
//
#include <hip/hip_runtime.h>
#include <hip/hip_bf16.h>
#include <math.h>

#define DIMC   256
#define LSP    4096
#define BATCH  8
#define DINNER 512
#define NHEADS 8
#define HEADDIM 64
#define DSTATE 64
#define CONVDIM 640
#define DPROJ  1160
#define MPAD   1280
#define CHUNK  256
#define NCHUNK 16

typedef unsigned short u16;
typedef __attribute__((ext_vector_type(8))) unsigned short u16x8;
typedef __attribute__((ext_vector_type(8))) short s16x8;
typedef __attribute__((ext_vector_type(4))) float f32x4;

#define MFMA16(a,b,c) __builtin_amdgcn_mfma_f32_16x16x32_bf16((s16x8)(a),(s16x8)(b),(c),0,0,0)

__device__ __forceinline__ float bf2f(u16 u){ return __uint_as_float(((unsigned int)u)<<16); }
__device__ __forceinline__ u16 f2bf(float f){
  unsigned int x = __float_as_uint(f);
  unsigned int r = (x + 0x7fffu + ((x>>16)&1u)) >> 16;
  return (u16)r;
}
__device__ __forceinline__ float softplusf(float x){ return (x > 20.f) ? x : __logf(1.f + __expf(x)); }
__device__ __forceinline__ float siluf(float x){ return x * __builtin_amdgcn_rcpf(1.f + __expf(-x)); }

// ---------------- weight fp32 -> bf16 (with trailing-row zero pad) ----------------
__global__ void convert_w(const float* __restrict__ src, u16* __restrict__ dst,
                          int total, int valid){
  int i = blockIdx.x*256 + threadIdx.x;
  if (i >= total) return;
  dst[i] = (i < valid) ? f2bf(src[i]) : (u16)0;
}

// ---------------- out_proj weight * rmsw fold -> bf16 ----------------
__global__ void convert_w_rms(const float* __restrict__ src, const float* __restrict__ rmsw,
                              u16* __restrict__ dst){
  int i = blockIdx.x*256 + threadIdx.x;
  if (i >= DIMC*DINNER) return;
  dst[i] = f2bf(src[i] * rmsw[i & (DINNER-1)]);
}

// ---------------- LayerNorm: x [b][c][l] fp32 -> XNT [b][l][c] bf16 ----------------
__global__ void ln_kernel(const float* __restrict__ X, const float* __restrict__ lnw,
                          const float* __restrict__ lnb, u16* __restrict__ XNT) {
  int pos = blockIdx.x*256 + threadIdx.x;
  int b = pos >> 12, l = pos & (LSP-1);
  const float* xb = X + ((size_t)b*DIMC)*LSP + l;
  float sum=0.f, sq=0.f;
  for (int c=0;c<DIMC;c++){ float v=xb[(size_t)c*LSP]; sum+=v; sq+=v*v; }
  float mu = sum*(1.f/DIMC);
  float var = sq*(1.f/DIMC) - mu*mu;
  float rs = rsqrtf(var + 1e-5f);
  u16* ob = XNT + ((size_t)(b*LSP + l))*DIMC;
  for (int c0=0;c0<DIMC;c0+=8){
    u16x8 v8;
    #pragma unroll
    for(int j=0;j<8;j++){
      float v = xb[(size_t)(c0+j)*LSP];
      v8[j] = f2bf((v-mu)*rs*lnw[c0+j] + lnb[c0+j]);
    }
    *(u16x8*)&ob[c0] = v8;
  }
}

// ---------------- Fused in_proj GEMM: XNT tile LDS-resident, loop over 5 proj tiles.
__global__ __launch_bounds__(256,2) void gemm_in_fused(
    const u16* __restrict__ W, const u16* __restrict__ XNT,
    u16* __restrict__ ZT, u16* __restrict__ XBC, u16* __restrict__ DT){
  __shared__ u16 Xs[128][264];
  __shared__ u16 Ws[128][32];
  int tid=threadIdx.x, w=tid>>6, lane=tid&63, l15=lane&15, quad=lane>>4;
  int n0=blockIdx.x*128, mh=blockIdx.y, b=blockIdx.z;
  {
    const u16* src = XNT + ((size_t)(b*LSP + n0))*DIMC;
    #pragma unroll
    for (int i=0;i<16;i++){
      int g = i*256 + tid;
      int row = g>>5, c8 = (g&31)*8;
      *(u16x8*)&Xs[row][c8] = *(const u16x8*)&src[(size_t)row*DIMC + c8];
    }
  }
  for (int pti=0; pti<5; pti++){
    int ptg = mh*5 + pti;
    int m0 = ptg*128;
    f32x4 acc[4][4];
    #pragma unroll
    for(int i=0;i<4;i++)
      #pragma unroll
      for(int j=0;j<4;j++) acc[i][j]=(f32x4){0.f,0.f,0.f,0.f};
    for (int k0=0;k0<DIMC;k0+=32){
      __syncthreads();
      {
        int ch = tid*2;
        int r = ch>>2, o=(ch&3)*8;
        *(u16x8*)&Ws[r][o] = *(const u16x8*)&W[(size_t)(m0+r)*DIMC + k0 + o];
        ch++; r = ch>>2; o=(ch&3)*8;
        *(u16x8*)&Ws[r][o] = *(const u16x8*)&W[(size_t)(m0+r)*DIMC + k0 + o];
      }
      __syncthreads();
      u16x8 af[4], bfr[4];
      if (ptg < 4){
        #pragma unroll
        for(int mt=0;mt<4;mt++) af[mt] = *(const u16x8*)&Xs[(w>>1)*64+mt*16+l15][k0+quad*8];
        #pragma unroll
        for(int nt=0;nt<4;nt++) bfr[nt] = *(const u16x8*)&Ws[(w&1)*64+nt*16+l15][quad*8];
      } else {
        #pragma unroll
        for(int mt=0;mt<4;mt++) af[mt] = *(const u16x8*)&Ws[(w>>1)*64+mt*16+l15][quad*8];
        #pragma unroll
        for(int nt=0;nt<4;nt++) bfr[nt] = *(const u16x8*)&Xs[(w&1)*64+nt*16+l15][k0+quad*8];
      }
      #pragma unroll
      for(int mt=0;mt<4;mt++)
        #pragma unroll
        for(int nt=0;nt<4;nt++)
          acc[mt][nt]=MFMA16(af[mt],bfr[nt],acc[mt][nt]);
    }
    if (ptg < 4){
      #pragma unroll
      for(int mt=0;mt<4;mt++)
        #pragma unroll
        for(int nt=0;nt<4;nt++)
          #pragma unroll
          for(int r=0;r<4;r++){
            int lrow = n0 + (w>>1)*64 + mt*16 + quad*4 + r;
            int dcol = m0 + (w&1)*64 + nt*16 + l15;
            ZT[((size_t)b*LSP + lrow)*DINNER + dcol] = f2bf(acc[mt][nt][r]);
          }
    } else {
      #pragma unroll
      for(int mt=0;mt<4;mt++)
        #pragma unroll
        for(int nt=0;nt<4;nt++)
          #pragma unroll
          for(int r=0;r<4;r++){
            int prow = m0 + (w>>1)*64 + mt*16 + quad*4 + r;
            if (prow>=DPROJ) continue;
            int col = n0 + (w&1)*64 + nt*16 + l15;
            u16 v = f2bf(acc[mt][nt][r]);
            if (prow<DINNER+CONVDIM)  XBC[((size_t)b*CONVDIM+(prow-DINNER))*LSP+col]=v;
            else                      DT[((size_t)b*NHEADS+(prow-DINNER-CONVDIM))*LSP+col]=v;
          }
    }
  }
}

// ---------------- GEMM2 (MFMA): W2' [256x512] x g [b,l,512], *rinv[l] + x -> fp32 ----
__global__ void gemm_out_mfma(const u16* __restrict__ A, const u16* __restrict__ Bm,
                              const float* __restrict__ Res, float* __restrict__ Out){
  __shared__ u16 As[128][32];
  __shared__ u16 Bs[128][32];
  __shared__ float rinv[128];
  int tid=threadIdx.x, w=tid>>6, lane=tid&63, l15=lane&15, quad=lane>>4;
  int b=blockIdx.z, m0=blockIdx.y*128, n0=blockIdx.x*128;
  const u16* Bb = Bm + ((size_t)b*LSP + n0)*DINNER;
  for (int rr=w; rr<128; rr+=4){
    u16x8 v = *(const u16x8*)&Bb[(size_t)rr*DINNER + lane*8];
    float s=0.f;
    #pragma unroll
    for(int j=0;j<8;j++){ float f=bf2f(v[j]); s+=f*f; }
    #pragma unroll
    for(int o=32;o>0;o>>=1) s += __shfl_xor(s,o,64);
    if (lane==0) rinv[rr] = rsqrtf(s*(1.f/DINNER) + 1e-5f);
  }
  f32x4 acc[4][4];
  #pragma unroll
  for(int i=0;i<4;i++)
    #pragma unroll
    for(int j=0;j<4;j++) acc[i][j] = (f32x4){0.f,0.f,0.f,0.f};
  for (int k0=0;k0<DINNER;k0+=32){
    __syncthreads();
    {
      int ch = tid*2;
      int r = ch>>2, o=(ch&3)*8;
      *(u16x8*)&As[r][o] = *(const u16x8*)&A[(size_t)(m0+r)*DINNER + k0 + o];
      *(u16x8*)&Bs[r][o] = *(const u16x8*)&Bb[(size_t)r*DINNER + k0 + o];
      ch++; r = ch>>2; o=(ch&3)*8;
      *(u16x8*)&As[r][o] = *(const u16x8*)&A[(size_t)(m0+r)*DINNER + k0 + o];
      *(u16x8*)&Bs[r][o] = *(const u16x8*)&Bb[(size_t)r*DINNER + k0 + o];
    }
    __syncthreads();
    u16x8 af[4], bfr[4];
    #pragma unroll
    for(int mt=0;mt<4;mt++) af[mt] = *(const u16x8*)&As[(w>>1)*64+mt*16+l15][quad*8];
    #pragma unroll
    for(int nt=0;nt<4;nt++) bfr[nt] = *(const u16x8*)&Bs[(w&1)*64+nt*16+l15][quad*8];
    #pragma unroll
    for(int mt=0;mt<4;mt++)
      #pragma unroll
      for(int nt=0;nt<4;nt++)
        acc[mt][nt]=MFMA16(af[mt],bfr[nt],acc[mt][nt]);
  }
  #pragma unroll
  for(int mt=0;mt<4;mt++)
    #pragma unroll
    for(int nt=0;nt<4;nt++){
      float rv = rinv[(w&1)*64 + nt*16 + l15];
      #pragma unroll
      for(int r=0;r<4;r++){
        int row = m0 + (w>>1)*64 + mt*16 + quad*4 + r;
        int col = n0 + (w&1)*64 + nt*16 + l15;
        size_t oi = ((size_t)b*DIMC+row)*LSP+col;
        Out[oi] = acc[mt][nt][r]*rv + Res[oi];
      }
    }
}

// ---------------- Depthwise 3x3 conv + bias + SiLU, IN-PLACE on XBC ----------------
__global__ void conv_kernel(u16* __restrict__ XBC, const float* __restrict__ CW,
                            const float* __restrict__ CB){
  int ch = blockIdx.x, b = blockIdx.y, tid = threadIdx.x;
  __shared__ float plane[66*66];
  u16* base = XBC + ((size_t)b*CONVDIM + ch)*LSP;
  for (int idx=tid; idx<66*66; idx+=256){
    int yy = idx/66 - 1, xx = idx%66 - 1;
    float v = 0.f;
    if (yy>=0 && yy<64 && xx>=0 && xx<64) v = bf2f(base[yy*64+xx]);
    plane[idx] = v;
  }
  float wg[9];
  #pragma unroll
  for (int t=0;t<9;t++) wg[t] = CW[ch*9+t];
  float bias = CB[ch];
  __syncthreads();
  for (int r=0;r<16;r++){
    int pix = tid + r*256;
    int y = pix>>6, x = pix&63;
    float s=0.f;
    #pragma unroll
    for(int dy=0;dy<3;dy++)
      #pragma unroll
      for(int dx=0;dx<3;dx++) s += plane[(y+dy)*66 + x+dx]*wg[dy*3+dx];
    base[pix] = f2bf(siluf(s + bias));
  }
}

// ---------------- SSD pre: dt softplus + per-chunk cumsum, done ONCE ----------------
__global__ void ssd_pre_kernel(const u16* __restrict__ DT, const float* __restrict__ A_log,
                               const float* __restrict__ dt_bias, float* __restrict__ ACS,
                               float* __restrict__ DTV, float* __restrict__ DASUM){
  int c=blockIdx.x, h=blockIdx.y, b=blockIdx.z, tid=threadIdx.x;
  __shared__ float acs[CHUNK];
  size_t base = ((size_t)b*NHEADS+h)*LSP + c*CHUNK + tid;
  float raw = bf2f(DT[base]);
  float dtv = softplusf(raw + dt_bias[h]);
  float Ah = -__expf(A_log[h]);
  acs[tid] = dtv*Ah;
  __syncthreads();
  for(int o=1;o<256;o<<=1){
    float add=(tid>=o)?acs[tid-o]:0.f;
    __syncthreads(); acs[tid]+=add; __syncthreads();
  }
  ACS[base] = acs[tid];
  DTV[base] = dtv;
  if (tid==CHUNK-1) DASUM[((size_t)b*NHEADS+h)*NCHUNK+c] = acs[tid];
}

// ---------------- SSD states (MFMA): states_T[p][n] = sum_t Xdtw[t][p]*B[t][n] ------
__global__ __launch_bounds__(256,4) void ssd_states_mfma(
    const float* __restrict__ ACS, const float* __restrict__ DTV,
    const float* __restrict__ DASUM, const u16* __restrict__ XBC,
    float* __restrict__ STATES){
  int c=blockIdx.x, h=blockIdx.y, b=blockIdx.z;
  int tid=threadIdx.x, w=tid>>6, lane=tid&63, l15=lane&15, quad=lane>>4;
  __shared__ float wdt[CHUNK];
  __shared__ u16 Xw[64][136];
  __shared__ u16 Bn[64][136];
  {
    size_t base = ((size_t)b*NHEADS+h)*LSP + c*CHUNK + tid;
    float atot = DASUM[((size_t)b*NHEADS+h)*NCHUNK+c];
    wdt[tid] = DTV[base]*__expf(atot - ACS[base]);
  }
  __syncthreads();
  f32x4 acc[4];
  #pragma unroll
  for(int i=0;i<4;i++) acc[i] = (f32x4){0.f,0.f,0.f,0.f};
  size_t cb = (size_t)c*CHUNK;
  for(int th=0; th<2; th++){
    __syncthreads();
    {
      int n=tid&63, q4=tid>>6;
      const u16* Xg = XBC + ((size_t)b*CONVDIM + h*HEADDIM + n)*LSP + cb + th*128;
      const u16* Bg = XBC + ((size_t)b*CONVDIM + DINNER + n)*LSP + cb + th*128;
      #pragma unroll
      for(int i=0;i<4;i++){
        int o = q4*32+i*8;
        u16x8 v = *(const u16x8*)&Xg[o];
        u16x8 wv;
        #pragma unroll
        for(int j=0;j<8;j++) wv[j]=f2bf(bf2f(v[j])*wdt[th*128+o+j]);
        *(u16x8*)&Xw[n][o]=wv;
        *(u16x8*)&Bn[n][o] = *(const u16x8*)&Bg[o];
      }
    }
    __syncthreads();
    #pragma unroll
    for(int k8=0;k8<4;k8++){
      u16x8 a = *(const u16x8*)&Xw[w*16+l15][k8*32+quad*8];
      #pragma unroll
      for(int nt=0;nt<4;nt++){
        u16x8 bb = *(const u16x8*)&Bn[nt*16+l15][k8*32+quad*8];
        acc[nt]=MFMA16(a,bb,acc[nt]);
      }
    }
  }
  float* dst = STATES + (((size_t)b*NHEADS+h)*NCHUNK+c)*4096;
  #pragma unroll
  for(int nt=0;nt<4;nt++)
    #pragma unroll
    for(int r=0;r<4;r++)
      dst[(w*16+quad*4+r)*64 + nt*16+l15] = acc[nt][r];
}

// ---------------- inter-chunk scan -> PREVB bf16 [p][n] per (b,h,c) ----------------
__global__ void ssd_scan_kernel(const float* __restrict__ STATES, const float* __restrict__ DASUM,
                                u16* __restrict__ PREVB){
  int g = blockIdx.x, h = blockIdx.y, b = blockIdx.z, tid = threadIdx.x;
  int e = g*256 + tid;
  size_t hb = (size_t)b*NHEADS + h;
  size_t base = hb*NCHUNK*4096 + e;
  float s = 0.f;
  for (int cc=0;cc<NCHUNK;cc++){
    PREVB[base + (size_t)cc*4096] = f2bf(s);
    s = s*__expf(DASUM[hb*NCHUNK + cc]) + STATES[base + (size_t)cc*4096];
  }
}

// ---------------- SSD Y (MFMA, band per block): C gathered once, LDS 29.7KB ---------
__global__ __launch_bounds__(256,5) void ssd_y_mfma(
    const float* __restrict__ ACS, const float* __restrict__ DTV,
    const u16* __restrict__ XBC, const float* __restrict__ Dp,
    const u16* __restrict__ PREVB, const u16* __restrict__ ZT,
    u16* __restrict__ YG){
  int bx = blockIdx.x; int c = bx>>2, tb = bx&3;
  int h = blockIdx.y, b = blockIdx.z;
  int tid=threadIdx.x, w=tid>>6, lane=tid&63, l15=lane&15, quad=lane>>4;
  __shared__ float acs[CHUNK];
  __shared__ float dtv[CHUNK];
  __shared__ u16 Bsb[64][72];
  __shared__ u16 Xsb[64][72];
  __shared__ u16 P[4][16][72];
  {
    size_t base = ((size_t)b*NHEADS+h)*LSP + c*CHUNK + tid;
    acs[tid] = ACS[base];
    dtv[tid] = DTV[base];
  }
  // C fragment: once-per-block strided gather (out of loop — no LDS, no transpose)
  u16x8 ca0, ca1;
  {
    const u16* Cbase = XBC + ((size_t)b*CONVDIM + DINNER + DSTATE)*LSP
                     + (size_t)c*CHUNK + tb*64 + w*16 + l15;
    #pragma unroll
    for(int j=0;j<8;j++){
      ca0[j] = Cbase[(size_t)(quad*8+j)*LSP];
      ca1[j] = Cbase[(size_t)(32+quad*8+j)*LSP];
    }
  }
  __syncthreads();
  f32x4 Yd[4], Yo[4];
  #pragma unroll
  for(int i=0;i<4;i++){ Yd[i]=(f32x4){0.f,0.f,0.f,0.f}; Yo[i]=(f32x4){0.f,0.f,0.f,0.f}; }
  // Y_off (unscaled): C . prev
  {
    const u16* Pg = PREVB + (((size_t)b*NHEADS+h)*NCHUNK + c)*4096;
    #pragma unroll
    for(int pt=0;pt<4;pt++){
      u16x8 b0 = *(const u16x8*)&Pg[(pt*16+l15)*64 + quad*8];
      u16x8 b1 = *(const u16x8*)&Pg[(pt*16+l15)*64 + 32 + quad*8];
      Yo[pt]=MFMA16(ca0,b0,Yo[pt]);
      Yo[pt]=MFMA16(ca1,b1,Yo[pt]);
    }
  }
  int tloc = tb*64 + w*16 + quad*4;
  float acst[4];
  #pragma unroll
  for(int r=0;r<4;r++) acst[r] = acs[tloc+r];
  float Dh = Dp[h];
  // causal blocks; B/X staged coalesced into LDS (m97 pattern), dtv and D folded into P
  for(int sb=0; sb<=tb; sb++){
    __syncthreads();
    {
      int n=tid&63, q4=tid>>6;
      const u16* Bg = XBC + ((size_t)b*CONVDIM + DINNER + n)*LSP + (size_t)c*CHUNK + sb*64;
      #pragma unroll
      for(int i=0;i<2;i++){
        u16x8 v = *(const u16x8*)&Bg[q4*16+i*8];
        #pragma unroll
        for(int j=0;j<8;j++) Bsb[q4*16+i*8+j][n]=v[j];
      }
      const u16* Xg = XBC + ((size_t)b*CONVDIM + h*HEADDIM + n)*LSP + (size_t)c*CHUNK + sb*64;
      #pragma unroll
      for(int i=0;i<2;i++){
        int o = q4*16+i*8;
        *(u16x8*)&Xsb[n][o] = *(const u16x8*)&Xg[o];
      }
    }
    __syncthreads();
    f32x4 S[4];
    #pragma unroll
    for(int st=0;st<4;st++){
      S[st]=(f32x4){0.f,0.f,0.f,0.f};
      u16x8 b0 = *(const u16x8*)&Bsb[st*16+l15][quad*8];
      u16x8 b1 = *(const u16x8*)&Bsb[st*16+l15][32+quad*8];
      S[st]=MFMA16(ca0,b0,S[st]);
      S[st]=MFMA16(ca1,b1,S[st]);
    }
    if (sb < tb){
      #pragma unroll
      for(int st=0;st<4;st++){
        int s = sb*64 + st*16 + l15;
        float as = acs[s], dv = dtv[s];
        #pragma unroll
        for(int r=0;r<4;r++)
          P[w][quad*4+r][st*16+l15] = f2bf(S[st][r]*__expf(acst[r]-as)*dv);
      }
    } else {
      #pragma unroll
      for(int st=0;st<4;st++){
        int s = sb*64 + st*16 + l15;
        float as = acs[s], dv = dtv[s];
        #pragma unroll
        for(int r=0;r<4;r++){
          int t = tloc + r;
          float pv;
          if (s < t)       pv = S[st][r]*__expf(acst[r]-as)*dv;
          else if (s == t) pv = S[st][r]*dv + Dh;
          else             pv = 0.f;
          P[w][quad*4+r][st*16+l15] = f2bf(pv);
        }
      }
    }
    u16x8 p0 = *(const u16x8*)&P[w][l15][quad*8];
    u16x8 p1 = *(const u16x8*)&P[w][l15][32+quad*8];
    #pragma unroll
    for(int pt=0;pt<4;pt++){
      u16x8 x0 = *(const u16x8*)&Xsb[pt*16+l15][quad*8];
      u16x8 x1 = *(const u16x8*)&Xsb[pt*16+l15][32+quad*8];
      Yd[pt]=MFMA16(p0,x0,Yd[pt]);
      Yd[pt]=MFMA16(p1,x1,Yd[pt]);
    }
  }
  // epilogue: y = Yd + exp(acs[t])*Yo; gate with silu(z); write YG [l][d]
  float eat[4];
  #pragma unroll
  for(int r=0;r<4;r++) eat[r] = __expf(acst[r]);
  size_t lbase = (size_t)b*LSP + c*CHUNK + tb*64;
  #pragma unroll
  for(int pt=0;pt<4;pt++){
    #pragma unroll
    for(int r=0;r<4;r++){
      int tl = w*16 + quad*4 + r;
      int p = pt*16 + l15;
      float y = Yd[pt][r] + eat[r]*Yo[pt][r];
      size_t oi = (lbase + tl)*DINNER + h*HEADDIM + p;
      float zv = bf2f(ZT[oi]);
      YG[oi] = f2bf(y * siluf(zv));
    }
  }
}

extern "C" void kernel_launch(void* const* d_in, const int* in_sizes, int n_in,
                              void* d_out, int out_size, void* d_ws, size_t ws_size,
                              hipStream_t stream) {
  const float* x     = (const float*)d_in[0];
  const float* lnw   = (const float*)d_in[1];
  const float* lnb   = (const float*)d_in[2];
  const float* inpw  = (const float*)d_in[3];
  const float* convw = (const float*)d_in[4];
  const float* convb = (const float*)d_in[5];
  const float* alog  = (const float*)d_in[6];
  const float* Dp    = (const float*)d_in[7];
  const float* dtbi  = (const float*)d_in[8];
  const float* rmsw  = (const float*)d_in[9];
  const float* outw  = (const float*)d_in[10];
  float* out = (float*)d_out;

  char* ws = (char*)d_ws;
  size_t off = 0;
  auto alloc = [&](size_t bytes)->void*{ void* p = ws+off; off += (bytes+255)&~(size_t)255; return p; };
  u16*   WPIN   = (u16*)  alloc((size_t)MPAD*DIMC*2);
  u16*   WPOUT  = (u16*)  alloc((size_t)DIMC*DINNER*2);
  char*  RA     = (char*) alloc((size_t)BATCH*NHEADS*NCHUNK*4096*4);
  u16*   XNT    = (u16*)RA;
  float* STATES = (float*)RA;
  u16*   ZT     = (u16*)  alloc((size_t)BATCH*LSP*DINNER*2);
  u16*   XBC    = (u16*)  alloc((size_t)BATCH*CONVDIM*LSP*2);
  u16*   DTb    = (u16*)  alloc((size_t)BATCH*NHEADS*LSP*2);
  u16*   PREVB  = (u16*)  alloc((size_t)BATCH*NHEADS*NCHUNK*4096*2);
  float* DASUM  = (float*)alloc((size_t)BATCH*NHEADS*NCHUNK*4);
  float* ACS    = (float*)alloc((size_t)BATCH*NHEADS*LSP*4);
  float* DTV    = (float*)alloc((size_t)BATCH*NHEADS*LSP*4);
  u16*   YG     = (u16*)  alloc((size_t)BATCH*LSP*DINNER*2);

  convert_w<<<(MPAD*DIMC+255)/256,256,0,stream>>>(inpw, WPIN, MPAD*DIMC, DPROJ*DIMC);
  convert_w_rms<<<(DIMC*DINNER+255)/256,256,0,stream>>>(outw, rmsw, WPOUT);
  ln_kernel<<<dim3(BATCH*LSP/256),256,0,stream>>>(x,lnw,lnb,XNT);
  gemm_in_fused<<<dim3(LSP/128,2,BATCH),256,0,stream>>>(WPIN, XNT, ZT, XBC, DTb);
  conv_kernel<<<dim3(CONVDIM,BATCH),256,0,stream>>>(XBC, convw, convb);
  ssd_pre_kernel<<<dim3(NCHUNK,NHEADS,BATCH),256,0,stream>>>(DTb, alog, dtbi, ACS, DTV, DASUM);
  ssd_states_mfma<<<dim3(NCHUNK,NHEADS,BATCH),256,0,stream>>>(ACS,DTV,DASUM,XBC,STATES);
  ssd_scan_kernel<<<dim3(16,NHEADS,BATCH),256,0,stream>>>(STATES,DASUM,PREVB);
  ssd_y_mfma<<<dim3(NCHUNK*4,NHEADS,BATCH),256,0,stream>>>(ACS,DTV,XBC,Dp,PREVB,ZT,YG);
  gemm_out_mfma<<<dim3(LSP/128,DIMC/128,BATCH),256,0,stream>>>(WPOUT, YG, x, out);
}

// Round 13
// 344.082 us; speedup vs baseline: 1.2917x; 1.0193x over previous
//
#include <hip/hip_runtime.h>
#include <hip/hip_bf16.h>
#include <math.h>

#define DIMC   256
#define LSP    4096
#define BATCH  8
#define DINNER 512
#define NHEADS 8
#define HEADDIM 64
#define DSTATE 64
#define CONVDIM 640
#define DPROJ  1160
#define MPAD   1280
#define CHUNK  256
#define NCHUNK 16

typedef unsigned short u16;
typedef __attribute__((ext_vector_type(8))) unsigned short u16x8;
typedef __attribute__((ext_vector_type(8))) short s16x8;
typedef __attribute__((ext_vector_type(4))) float f32x4;

#define MFMA16(a,b,c) __builtin_amdgcn_mfma_f32_16x16x32_bf16((s16x8)(a),(s16x8)(b),(c),0,0,0)

__device__ __forceinline__ float bf2f(u16 u){ return __uint_as_float(((unsigned int)u)<<16); }
__device__ __forceinline__ u16 f2bf(float f){
  unsigned int x = __float_as_uint(f);
  unsigned int r = (x + 0x7fffu + ((x>>16)&1u)) >> 16;
  return (u16)r;
}
__device__ __forceinline__ float softplusf(float x){ return (x > 20.f) ? x : __logf(1.f + __expf(x)); }
__device__ __forceinline__ float siluf(float x){ return x * __builtin_amdgcn_rcpf(1.f + __expf(-x)); }

// ---------------- weight fp32 -> bf16 (with trailing-row zero pad) ----------------
__global__ void convert_w(const float* __restrict__ src, u16* __restrict__ dst,
                          int total, int valid){
  int i = blockIdx.x*256 + threadIdx.x;
  if (i >= total) return;
  dst[i] = (i < valid) ? f2bf(src[i]) : (u16)0;
}

// ---------------- out_proj weight * rmsw fold -> bf16 ----------------
__global__ void convert_w_rms(const float* __restrict__ src, const float* __restrict__ rmsw,
                              u16* __restrict__ dst){
  int i = blockIdx.x*256 + threadIdx.x;
  if (i >= DIMC*DINNER) return;
  dst[i] = f2bf(src[i] * rmsw[i & (DINNER-1)]);
}

// ---------------- LayerNorm: x [b][c][l] fp32 -> XNT [b][l][c] bf16 ----------------
__global__ void ln_kernel(const float* __restrict__ X, const float* __restrict__ lnw,
                          const float* __restrict__ lnb, u16* __restrict__ XNT) {
  int pos = blockIdx.x*256 + threadIdx.x;
  int b = pos >> 12, l = pos & (LSP-1);
  const float* xb = X + ((size_t)b*DIMC)*LSP + l;
  float sum=0.f, sq=0.f;
  for (int c=0;c<DIMC;c++){ float v=xb[(size_t)c*LSP]; sum+=v; sq+=v*v; }
  float mu = sum*(1.f/DIMC);
  float var = sq*(1.f/DIMC) - mu*mu;
  float rs = rsqrtf(var + 1e-5f);
  u16* ob = XNT + ((size_t)(b*LSP + l))*DIMC;
  for (int c0=0;c0<DIMC;c0+=8){
    u16x8 v8;
    #pragma unroll
    for(int j=0;j<8;j++){
      float v = xb[(size_t)(c0+j)*LSP];
      v8[j] = f2bf((v-mu)*rs*lnw[c0+j] + lnb[c0+j]);
    }
    *(u16x8*)&ob[c0] = v8;
  }
}

// ---------------- Fused in_proj GEMM: XNT tile LDS-resident, loop over 5 proj tiles.
__global__ __launch_bounds__(256,2) void gemm_in_fused(
    const u16* __restrict__ W, const u16* __restrict__ XNT,
    u16* __restrict__ ZT, u16* __restrict__ XBC, u16* __restrict__ DT){
  __shared__ u16 Xs[128][264];
  __shared__ u16 Ws[128][32];
  int tid=threadIdx.x, w=tid>>6, lane=tid&63, l15=lane&15, quad=lane>>4;
  int n0=blockIdx.x*128, mh=blockIdx.y, b=blockIdx.z;
  {
    const u16* src = XNT + ((size_t)(b*LSP + n0))*DIMC;
    #pragma unroll
    for (int i=0;i<16;i++){
      int g = i*256 + tid;
      int row = g>>5, c8 = (g&31)*8;
      *(u16x8*)&Xs[row][c8] = *(const u16x8*)&src[(size_t)row*DIMC + c8];
    }
  }
  for (int pti=0; pti<5; pti++){
    int ptg = mh*5 + pti;
    int m0 = ptg*128;
    f32x4 acc[4][4];
    #pragma unroll
    for(int i=0;i<4;i++)
      #pragma unroll
      for(int j=0;j<4;j++) acc[i][j]=(f32x4){0.f,0.f,0.f,0.f};
    for (int k0=0;k0<DIMC;k0+=32){
      __syncthreads();
      {
        int ch = tid*2;
        int r = ch>>2, o=(ch&3)*8;
        *(u16x8*)&Ws[r][o] = *(const u16x8*)&W[(size_t)(m0+r)*DIMC + k0 + o];
        ch++; r = ch>>2; o=(ch&3)*8;
        *(u16x8*)&Ws[r][o] = *(const u16x8*)&W[(size_t)(m0+r)*DIMC + k0 + o];
      }
      __syncthreads();
      u16x8 af[4], bfr[4];
      if (ptg < 4){
        #pragma unroll
        for(int mt=0;mt<4;mt++) af[mt] = *(const u16x8*)&Xs[(w>>1)*64+mt*16+l15][k0+quad*8];
        #pragma unroll
        for(int nt=0;nt<4;nt++) bfr[nt] = *(const u16x8*)&Ws[(w&1)*64+nt*16+l15][quad*8];
      } else {
        #pragma unroll
        for(int mt=0;mt<4;mt++) af[mt] = *(const u16x8*)&Ws[(w>>1)*64+mt*16+l15][quad*8];
        #pragma unroll
        for(int nt=0;nt<4;nt++) bfr[nt] = *(const u16x8*)&Xs[(w&1)*64+nt*16+l15][k0+quad*8];
      }
      #pragma unroll
      for(int mt=0;mt<4;mt++)
        #pragma unroll
        for(int nt=0;nt<4;nt++)
          acc[mt][nt]=MFMA16(af[mt],bfr[nt],acc[mt][nt]);
    }
    if (ptg < 4){
      #pragma unroll
      for(int mt=0;mt<4;mt++)
        #pragma unroll
        for(int nt=0;nt<4;nt++)
          #pragma unroll
          for(int r=0;r<4;r++){
            int lrow = n0 + (w>>1)*64 + mt*16 + quad*4 + r;
            int dcol = m0 + (w&1)*64 + nt*16 + l15;
            ZT[((size_t)b*LSP + lrow)*DINNER + dcol] = f2bf(acc[mt][nt][r]);
          }
    } else {
      #pragma unroll
      for(int mt=0;mt<4;mt++)
        #pragma unroll
        for(int nt=0;nt<4;nt++)
          #pragma unroll
          for(int r=0;r<4;r++){
            int prow = m0 + (w>>1)*64 + mt*16 + quad*4 + r;
            if (prow>=DPROJ) continue;
            int col = n0 + (w&1)*64 + nt*16 + l15;
            u16 v = f2bf(acc[mt][nt][r]);
            if (prow<DINNER+CONVDIM)  XBC[((size_t)b*CONVDIM+(prow-DINNER))*LSP+col]=v;
            else                      DT[((size_t)b*NHEADS+(prow-DINNER-CONVDIM))*LSP+col]=v;
          }
    }
  }
}

// ---------------- GEMM2 (MFMA): W2' [256x512] x g [b,l,512]; rms folded into loader ---
__global__ void gemm_out_mfma(const u16* __restrict__ A, const u16* __restrict__ Bm,
                              const float* __restrict__ Res, float* __restrict__ Out){
  __shared__ u16 As[128][32];
  __shared__ u16 Bs[128][32];
  __shared__ float rinv[128];
  int tid=threadIdx.x, w=tid>>6, lane=tid&63, l15=lane&15, quad=lane>>4;
  int b=blockIdx.z, m0=blockIdx.y*128, n0=blockIdx.x*128;
  const u16* Bb = Bm + ((size_t)b*LSP + n0)*DINNER;
  f32x4 acc[4][4];
  #pragma unroll
  for(int i=0;i<4;i++)
    #pragma unroll
    for(int j=0;j<4;j++) acc[i][j] = (f32x4){0.f,0.f,0.f,0.f};
  float sqacc = 0.f;
  for (int k0=0;k0<DINNER;k0+=32){
    __syncthreads();
    {
      int ch = tid*2;
      int r = ch>>2, o=(ch&3)*8;
      *(u16x8*)&As[r][o] = *(const u16x8*)&A[(size_t)(m0+r)*DINNER + k0 + o];
      u16x8 bv = *(const u16x8*)&Bb[(size_t)r*DINNER + k0 + o];
      *(u16x8*)&Bs[r][o] = bv;
      #pragma unroll
      for(int j=0;j<8;j++){ float f=bf2f(bv[j]); sqacc += f*f; }
      ch++; r = ch>>2; o=(ch&3)*8;
      *(u16x8*)&As[r][o] = *(const u16x8*)&A[(size_t)(m0+r)*DINNER + k0 + o];
      u16x8 bv2 = *(const u16x8*)&Bb[(size_t)r*DINNER + k0 + o];
      *(u16x8*)&Bs[r][o] = bv2;
      #pragma unroll
      for(int j=0;j<8;j++){ float f=bf2f(bv2[j]); sqacc += f*f; }
    }
    __syncthreads();
    u16x8 af[4], bfr[4];
    #pragma unroll
    for(int mt=0;mt<4;mt++) af[mt] = *(const u16x8*)&As[(w>>1)*64+mt*16+l15][quad*8];
    #pragma unroll
    for(int nt=0;nt<4;nt++) bfr[nt] = *(const u16x8*)&Bs[(w&1)*64+nt*16+l15][quad*8];
    #pragma unroll
    for(int mt=0;mt<4;mt++)
      #pragma unroll
      for(int nt=0;nt<4;nt++)
        acc[mt][nt]=MFMA16(af[mt],bfr[nt],acc[mt][nt]);
  }
  // pair (tid, tid^1) covers one g-row; reduce and publish rinv
  {
    float tot = sqacc + __shfl_xor(sqacc, 1, 64);
    if ((tid&1)==0) rinv[tid>>1] = rsqrtf(tot*(1.f/DINNER) + 1e-5f);
  }
  __syncthreads();
  #pragma unroll
  for(int mt=0;mt<4;mt++)
    #pragma unroll
    for(int nt=0;nt<4;nt++){
      float rv = rinv[(w&1)*64 + nt*16 + l15];
      #pragma unroll
      for(int r=0;r<4;r++){
        int row = m0 + (w>>1)*64 + mt*16 + quad*4 + r;
        int col = n0 + (w&1)*64 + nt*16 + l15;
        size_t oi = ((size_t)b*DIMC+row)*LSP+col;
        Out[oi] = acc[mt][nt][r]*rv + Res[oi];
      }
    }
}

// ---------------- Depthwise 3x3 conv + bias + SiLU, IN-PLACE on XBC ----------------
__global__ void conv_kernel(u16* __restrict__ XBC, const float* __restrict__ CW,
                            const float* __restrict__ CB){
  int ch = blockIdx.x, b = blockIdx.y, tid = threadIdx.x;
  __shared__ float plane[66*66];
  u16* base = XBC + ((size_t)b*CONVDIM + ch)*LSP;
  for (int idx=tid; idx<66*66; idx+=256){
    int yy = idx/66 - 1, xx = idx%66 - 1;
    float v = 0.f;
    if (yy>=0 && yy<64 && xx>=0 && xx<64) v = bf2f(base[yy*64+xx]);
    plane[idx] = v;
  }
  float wg[9];
  #pragma unroll
  for (int t=0;t<9;t++) wg[t] = CW[ch*9+t];
  float bias = CB[ch];
  __syncthreads();
  for (int r=0;r<16;r++){
    int pix = tid + r*256;
    int y = pix>>6, x = pix&63;
    float s=0.f;
    #pragma unroll
    for(int dy=0;dy<3;dy++)
      #pragma unroll
      for(int dx=0;dx<3;dx++) s += plane[(y+dy)*66 + x+dx]*wg[dy*3+dx];
    base[pix] = f2bf(siluf(s + bias));
  }
}

// ---------------- SSD pre: dt softplus + per-chunk cumsum, done ONCE ----------------
__global__ void ssd_pre_kernel(const u16* __restrict__ DT, const float* __restrict__ A_log,
                               const float* __restrict__ dt_bias, float* __restrict__ ACS,
                               float* __restrict__ DTV, float* __restrict__ DASUM){
  int c=blockIdx.x, h=blockIdx.y, b=blockIdx.z, tid=threadIdx.x;
  __shared__ float acs[CHUNK];
  size_t base = ((size_t)b*NHEADS+h)*LSP + c*CHUNK + tid;
  float raw = bf2f(DT[base]);
  float dtv = softplusf(raw + dt_bias[h]);
  float Ah = -__expf(A_log[h]);
  acs[tid] = dtv*Ah;
  __syncthreads();
  for(int o=1;o<256;o<<=1){
    float add=(tid>=o)?acs[tid-o]:0.f;
    __syncthreads(); acs[tid]+=add; __syncthreads();
  }
  ACS[base] = acs[tid];
  DTV[base] = dtv;
  if (tid==CHUNK-1) DASUM[((size_t)b*NHEADS+h)*NCHUNK+c] = acs[tid];
}

// ---------------- SSD states (MFMA): states_T[p][n] = sum_t Xdtw[t][p]*B[t][n] ------
__global__ __launch_bounds__(256,4) void ssd_states_mfma(
    const float* __restrict__ ACS, const float* __restrict__ DTV,
    const float* __restrict__ DASUM, const u16* __restrict__ XBC,
    float* __restrict__ STATES){
  int c=blockIdx.x, h=blockIdx.y, b=blockIdx.z;
  int tid=threadIdx.x, w=tid>>6, lane=tid&63, l15=lane&15, quad=lane>>4;
  __shared__ float wdt[CHUNK];
  __shared__ u16 Xw[64][136];
  __shared__ u16 Bn[64][136];
  {
    size_t base = ((size_t)b*NHEADS+h)*LSP + c*CHUNK + tid;
    float atot = DASUM[((size_t)b*NHEADS+h)*NCHUNK+c];
    wdt[tid] = DTV[base]*__expf(atot - ACS[base]);
  }
  __syncthreads();
  f32x4 acc[4];
  #pragma unroll
  for(int i=0;i<4;i++) acc[i] = (f32x4){0.f,0.f,0.f,0.f};
  size_t cb = (size_t)c*CHUNK;
  for(int th=0; th<2; th++){
    __syncthreads();
    {
      int n=tid&63, q4=tid>>6;
      const u16* Xg = XBC + ((size_t)b*CONVDIM + h*HEADDIM + n)*LSP + cb + th*128;
      const u16* Bg = XBC + ((size_t)b*CONVDIM + DINNER + n)*LSP + cb + th*128;
      #pragma unroll
      for(int i=0;i<4;i++){
        int o = q4*32+i*8;
        u16x8 v = *(const u16x8*)&Xg[o];
        u16x8 wv;
        #pragma unroll
        for(int j=0;j<8;j++) wv[j]=f2bf(bf2f(v[j])*wdt[th*128+o+j]);
        *(u16x8*)&Xw[n][o]=wv;
        *(u16x8*)&Bn[n][o] = *(const u16x8*)&Bg[o];
      }
    }
    __syncthreads();
    #pragma unroll
    for(int k8=0;k8<4;k8++){
      u16x8 a = *(const u16x8*)&Xw[w*16+l15][k8*32+quad*8];
      #pragma unroll
      for(int nt=0;nt<4;nt++){
        u16x8 bb = *(const u16x8*)&Bn[nt*16+l15][k8*32+quad*8];
        acc[nt]=MFMA16(a,bb,acc[nt]);
      }
    }
  }
  float* dst = STATES + (((size_t)b*NHEADS+h)*NCHUNK+c)*4096;
  #pragma unroll
  for(int nt=0;nt<4;nt++)
    #pragma unroll
    for(int r=0;r<4;r++)
      dst[(w*16+quad*4+r)*64 + nt*16+l15] = acc[nt][r];
}

// ---------------- inter-chunk scan -> PREVB bf16 [p][n] per (b,h,c) ----------------
__global__ void ssd_scan_kernel(const float* __restrict__ STATES, const float* __restrict__ DASUM,
                                u16* __restrict__ PREVB){
  int g = blockIdx.x, h = blockIdx.y, b = blockIdx.z, tid = threadIdx.x;
  int e = g*256 + tid;
  size_t hb = (size_t)b*NHEADS + h;
  size_t base = hb*NCHUNK*4096 + e;
  float s = 0.f;
  for (int cc=0;cc<NCHUNK;cc++){
    PREVB[base + (size_t)cc*4096] = f2bf(s);
    s = s*__expf(DASUM[hb*NCHUNK + cc]) + STATES[base + (size_t)cc*4096];
  }
}

// ---------------- SSD Y (MFMA, band per block): P aliased on B tile, 7 blk/CU -------
// grid (h, c*4+j, b); tb = 3-j (heavy bands first); consecutive blocks share B/C.
__global__ __launch_bounds__(256,7) void ssd_y_mfma(
    const float* __restrict__ ACS, const float* __restrict__ DTV,
    const u16* __restrict__ XBC, const float* __restrict__ Dp,
    const u16* __restrict__ PREVB, const u16* __restrict__ ZT,
    u16* __restrict__ YG){
  int h = blockIdx.x, bx = blockIdx.y, b = blockIdx.z;
  int c = bx>>2, tb = 3-(bx&3);
  int tid=threadIdx.x, w=tid>>6, lane=tid&63, l15=lane&15, quad=lane>>4;
  __shared__ float acs[CHUNK];
  __shared__ float dtv[CHUNK];
  __shared__ u16 BP[64][72];      // B tile; rows [w*16, w*16+16) reused as wave-w's P
  __shared__ u16 Xsb[64][72];
  {
    size_t base = ((size_t)b*NHEADS+h)*LSP + c*CHUNK + tid;
    acs[tid] = ACS[base];
    dtv[tid] = DTV[base];
  }
  // C fragment: once-per-block strided gather (out of loop)
  u16x8 ca0, ca1;
  {
    const u16* Cbase = XBC + ((size_t)b*CONVDIM + DINNER + DSTATE)*LSP
                     + (size_t)c*CHUNK + tb*64 + w*16 + l15;
    #pragma unroll
    for(int j=0;j<8;j++){
      ca0[j] = Cbase[(size_t)(quad*8+j)*LSP];
      ca1[j] = Cbase[(size_t)(32+quad*8+j)*LSP];
    }
  }
  __syncthreads();
  f32x4 Yd[4], Yo[4];
  #pragma unroll
  for(int i=0;i<4;i++){ Yd[i]=(f32x4){0.f,0.f,0.f,0.f}; Yo[i]=(f32x4){0.f,0.f,0.f,0.f}; }
  // Y_off (unscaled): C . prev
  {
    const u16* Pg = PREVB + (((size_t)b*NHEADS+h)*NCHUNK + c)*4096;
    #pragma unroll
    for(int pt=0;pt<4;pt++){
      u16x8 b0 = *(const u16x8*)&Pg[(pt*16+l15)*64 + quad*8];
      u16x8 b1 = *(const u16x8*)&Pg[(pt*16+l15)*64 + 32 + quad*8];
      Yo[pt]=MFMA16(ca0,b0,Yo[pt]);
      Yo[pt]=MFMA16(ca1,b1,Yo[pt]);
    }
  }
  int tloc = tb*64 + w*16 + quad*4;
  float acst[4];
  #pragma unroll
  for(int r=0;r<4;r++) acst[r] = acs[tloc+r];
  float Dh = Dp[h];
  for(int sb=0; sb<=tb; sb++){
    __syncthreads();
    {
      int n=tid&63, q4=tid>>6;
      const u16* Bg = XBC + ((size_t)b*CONVDIM + DINNER + n)*LSP + (size_t)c*CHUNK + sb*64;
      #pragma unroll
      for(int i=0;i<2;i++){
        u16x8 v = *(const u16x8*)&Bg[q4*16+i*8];
        #pragma unroll
        for(int j=0;j<8;j++) BP[q4*16+i*8+j][n]=v[j];
      }
      const u16* Xg = XBC + ((size_t)b*CONVDIM + h*HEADDIM + n)*LSP + (size_t)c*CHUNK + sb*64;
      #pragma unroll
      for(int i=0;i<2;i++){
        int o = q4*16+i*8;
        *(u16x8*)&Xsb[n][o] = *(const u16x8*)&Xg[o];
      }
    }
    __syncthreads();
    f32x4 S[4];
    #pragma unroll
    for(int st=0;st<4;st++){
      S[st]=(f32x4){0.f,0.f,0.f,0.f};
      u16x8 b0 = *(const u16x8*)&BP[st*16+l15][quad*8];
      u16x8 b1 = *(const u16x8*)&BP[st*16+l15][32+quad*8];
      S[st]=MFMA16(ca0,b0,S[st]);
      S[st]=MFMA16(ca1,b1,S[st]);
    }
    __syncthreads();  // all waves done reading B before P overwrites it
    if (sb < tb){
      #pragma unroll
      for(int st=0;st<4;st++){
        int s = sb*64 + st*16 + l15;
        float as = acs[s], dv = dtv[s];
        #pragma unroll
        for(int r=0;r<4;r++)
          BP[w*16+quad*4+r][st*16+l15] = f2bf(S[st][r]*__expf(acst[r]-as)*dv);
      }
    } else {
      #pragma unroll
      for(int st=0;st<4;st++){
        int s = sb*64 + st*16 + l15;
        float as = acs[s], dv = dtv[s];
        #pragma unroll
        for(int r=0;r<4;r++){
          int t = tloc + r;
          float pv;
          if (s < t)       pv = S[st][r]*__expf(acst[r]-as)*dv;
          else if (s == t) pv = S[st][r]*dv + Dh;
          else             pv = 0.f;
          BP[w*16+quad*4+r][st*16+l15] = f2bf(pv);
        }
      }
    }
    u16x8 p0 = *(const u16x8*)&BP[w*16+l15][quad*8];
    u16x8 p1 = *(const u16x8*)&BP[w*16+l15][32+quad*8];
    #pragma unroll
    for(int pt=0;pt<4;pt++){
      u16x8 x0 = *(const u16x8*)&Xsb[pt*16+l15][quad*8];
      u16x8 x1 = *(const u16x8*)&Xsb[pt*16+l15][32+quad*8];
      Yd[pt]=MFMA16(p0,x0,Yd[pt]);
      Yd[pt]=MFMA16(p1,x1,Yd[pt]);
    }
  }
  // epilogue: y = Yd + exp(acs[t])*Yo; gate with silu(z); write YG [l][d]
  float eat[4];
  #pragma unroll
  for(int r=0;r<4;r++) eat[r] = __expf(acst[r]);
  size_t lbase = (size_t)b*LSP + c*CHUNK + tb*64;
  #pragma unroll
  for(int pt=0;pt<4;pt++){
    #pragma unroll
    for(int r=0;r<4;r++){
      int tl = w*16 + quad*4 + r;
      int p = pt*16 + l15;
      float y = Yd[pt][r] + eat[r]*Yo[pt][r];
      size_t oi = (lbase + tl)*DINNER + h*HEADDIM + p;
      float zv = bf2f(ZT[oi]);
      YG[oi] = f2bf(y * siluf(zv));
    }
  }
}

extern "C" void kernel_launch(void* const* d_in, const int* in_sizes, int n_in,
                              void* d_out, int out_size, void* d_ws, size_t ws_size,
                              hipStream_t stream) {
  const float* x     = (const float*)d_in[0];
  const float* lnw   = (const float*)d_in[1];
  const float* lnb   = (const float*)d_in[2];
  const float* inpw  = (const float*)d_in[3];
  const float* convw = (const float*)d_in[4];
  const float* convb = (const float*)d_in[5];
  const float* alog  = (const float*)d_in[6];
  const float* Dp    = (const float*)d_in[7];
  const float* dtbi  = (const float*)d_in[8];
  const float* rmsw  = (const float*)d_in[9];
  const float* outw  = (const float*)d_in[10];
  float* out = (float*)d_out;

  char* ws = (char*)d_ws;
  size_t off = 0;
  auto alloc = [&](size_t bytes)->void*{ void* p = ws+off; off += (bytes+255)&~(size_t)255; return p; };
  u16*   WPIN   = (u16*)  alloc((size_t)MPAD*DIMC*2);
  u16*   WPOUT  = (u16*)  alloc((size_t)DIMC*DINNER*2);
  char*  RA     = (char*) alloc((size_t)BATCH*NHEADS*NCHUNK*4096*4);
  u16*   XNT    = (u16*)RA;
  float* STATES = (float*)RA;
  u16*   ZT     = (u16*)  alloc((size_t)BATCH*LSP*DINNER*2);
  u16*   XBC    = (u16*)  alloc((size_t)BATCH*CONVDIM*LSP*2);
  u16*   DTb    = (u16*)  alloc((size_t)BATCH*NHEADS*LSP*2);
  u16*   PREVB  = (u16*)  alloc((size_t)BATCH*NHEADS*NCHUNK*4096*2);
  float* DASUM  = (float*)alloc((size_t)BATCH*NHEADS*NCHUNK*4);
  float* ACS    = (float*)alloc((size_t)BATCH*NHEADS*LSP*4);
  float* DTV    = (float*)alloc((size_t)BATCH*NHEADS*LSP*4);
  u16*   YG     = (u16*)  alloc((size_t)BATCH*LSP*DINNER*2);

  convert_w<<<(MPAD*DIMC+255)/256,256,0,stream>>>(inpw, WPIN, MPAD*DIMC, DPROJ*DIMC);
  convert_w_rms<<<(DIMC*DINNER+255)/256,256,0,stream>>>(outw, rmsw, WPOUT);
  ln_kernel<<<dim3(BATCH*LSP/256),256,0,stream>>>(x,lnw,lnb,XNT);
  gemm_in_fused<<<dim3(LSP/128,2,BATCH),256,0,stream>>>(WPIN, XNT, ZT, XBC, DTb);
  conv_kernel<<<dim3(CONVDIM,BATCH),256,0,stream>>>(XBC, convw, convb);
  ssd_pre_kernel<<<dim3(NCHUNK,NHEADS,BATCH),256,0,stream>>>(DTb, alog, dtbi, ACS, DTV, DASUM);
  ssd_states_mfma<<<dim3(NCHUNK,NHEADS,BATCH),256,0,stream>>>(ACS,DTV,DASUM,XBC,STATES);
  ssd_scan_kernel<<<dim3(16,NHEADS,BATCH),256,0,stream>>>(STATES,DASUM,PREVB);
  ssd_y_mfma<<<dim3(NHEADS,NCHUNK*4,BATCH),256,0,stream>>>(ACS,DTV,XBC,Dp,PREVB,ZT,YG);
  gemm_out_mfma<<<dim3(LSP/128,DIMC/128,BATCH),256,0,stream>>>(WPOUT, YG, x, out);
}